// Round 12
// baseline (163.158 us; speedup 1.0000x reference)
//
#include <hip/hip_runtime.h>

// Fused tensor-field + 3-layer MLP for MI355X (gfx950). Round 11 resubmit.
//
// R8/R9/R10 all land at kernel ~40+-2us despite wildly different VALU counts
// and register pressure -> not issue-bound (floor ~9us), not spill-bound.
// Diagnosis: serialized phase structure (gather -> barrier -> f_T LDS
// round-trip -> compute) exposes dependent-load + barrier latency each block;
// MfmaUtil was 18%.
//
// This round: DELETE the phases. Direct per-lane gather in consuming layout:
// lane (lg,lr) gathers feats [8lg,8lg+8) of its pixel (8 f32x4 corner loads +
// 32 FMA -- same combine FLOPs as staged, no redundancy; idx/lerp reads are
// 4x redundant L1 broadcasts). Removes f_T, the gather barrier, and the LDS
// round-trip; after one-time weight/zf staging each wave is fully independent.
// Bias folded into MFMA C-operand. unroll 1 keeps live state ~135 VGPR
// (R9 lesson: don't let the unroller stage 32 corner loads).
//
// Compute core (verified R7-R10): transposed MFMA, sigma-striped L1 so lane's
// L1 accs are exactly its L2 B-frag k-run; h never leaves registers; L3 =
// in-register dot + 2 shfl_xor. 2-term split L1, 3-term L2.

typedef float f32x4 __attribute__((ext_vector_type(4)));
typedef short bf16x8 __attribute__((ext_vector_type(8)));

constexpr int NPIX = 512 * 512;
constexpr int PPB  = 64;    // pixels per block

union FragU { unsigned int u[4]; uint4 v; bf16x8 s; };

// D[15:0] = top16 of e0 (bf16 truncate), D[31:16] = top16 of e1
__device__ __forceinline__ unsigned int pack_top16(float e0, float e1) {
    return __builtin_amdgcn_perm(__float_as_uint(e1), __float_as_uint(e0), 0x07060302u);
}
__device__ __forceinline__ float trunc_bf16(float x) {
    return __uint_as_float(__float_as_uint(x) & 0xFFFF0000u);
}

__global__ __launch_bounds__(256) void field_mlp_mfma6(
    const float* __restrict__ z,        // [8]
    const float* __restrict__ data,     // [512,512,32]
    const float* __restrict__ z_data,   // [64,32]
    const float* __restrict__ lerp_w,   // [NPIX,2]
    const int* __restrict__ x0a, const int* __restrict__ y0a,
    const int* __restrict__ x1a, const int* __restrict__ y1a,
    const float* __restrict__ W1, const float* __restrict__ b1,
    const float* __restrict__ W2, const float* __restrict__ b2,
    const float* __restrict__ W3, const float* __restrict__ b3,
    float* __restrict__ out)            // [8,1,512,512]
{
    __shared__ float zf_lds[8][36];                      // [batch][feat]
    __shared__ float bias_lds[2][36];                    // b1, b2
    __shared__ float w3_lds[36];
    __shared__ __align__(16) unsigned int wt_lds[4][32][20]; // W1h,W1l,W2h,W2l [n][k-pairs]

    const int tid = threadIdx.x;

    // ---- one-time staging: z-feature, biases, weight transpose+split ----
    {
        const int b = tid >> 5, i = tid & 31;
        const float zn = 63.0f * z[b];               // Z_MIN=0, Z_MAX=1
        int z0 = (int)zn; z0 = max(0, min(z0, 63));
        const int z1i = min(z0 + 1, 63);
        const float zl = zn - truncf(zn);
        zf_lds[b][i] = z_data[z0 * 32 + i] * (1.0f - zl) + z_data[z1i * 32 + i] * zl;
    }
    if (tid < 32) {
        bias_lds[0][tid] = b1[tid];
        bias_lds[1][tid] = b2[tid];
        w3_lds[tid]      = W3[tid];
    }
    {
        const int n = tid & 31, kc = (tid >> 5) * 4, kw = (tid >> 5) * 2;
#pragma unroll
        for (int m = 0; m < 2; ++m) {
            const float* Wm = m ? W2 : W1;
            const float x0 = Wm[(kc + 0) * 32 + n];
            const float x1 = Wm[(kc + 1) * 32 + n];
            const float x2 = Wm[(kc + 2) * 32 + n];
            const float x3 = Wm[(kc + 3) * 32 + n];
            wt_lds[2 * m][n][kw]     = pack_top16(x0, x1);
            wt_lds[2 * m][n][kw + 1] = pack_top16(x2, x3);
            wt_lds[2 * m + 1][n][kw]     = pack_top16(x0 - trunc_bf16(x0), x1 - trunc_bf16(x1));
            wt_lds[2 * m + 1][n][kw + 1] = pack_top16(x2 - trunc_bf16(x2), x3 - trunc_bf16(x3));
        }
    }
    __syncthreads();                 // ONLY barrier in the kernel

    const int l  = tid & 63, w = tid >> 6;           // wave handles batches 2w, 2w+1
    const int lg = l >> 4,  lr = l & 15;
    const int srow = ((lr >> 2) << 3) + (lr & 3);    // sigma-stripe row for W1 tiles

    // ---- per-wave constant fragments ----
    FragU W1f[2][2], W2f[2][2];                      // [tile][hi=0/lo=1]
#pragma unroll
    for (int t = 0; t < 2; ++t) {
        W1f[t][0].v = *(const uint4*)&wt_lds[0][srow + 4 * t][lg * 4];
        W1f[t][1].v = *(const uint4*)&wt_lds[1][srow + 4 * t][lg * 4];
        W2f[t][0].v = *(const uint4*)&wt_lds[2][t * 16 + lr][lg * 4];
        W2f[t][1].v = *(const uint4*)&wt_lds[3][t * 16 + lr][lg * 4];
    }
    f32x4 zva[2], zvb[2], b1v[2], b2v[2], w3v[2];
#pragma unroll
    for (int bb = 0; bb < 2; ++bb) {
        zva[bb] = *(const f32x4*)&zf_lds[2 * w + bb][lg * 8];
        zvb[bb] = *(const f32x4*)&zf_lds[2 * w + bb][lg * 8 + 4];
    }
#pragma unroll
    for (int t = 0; t < 2; ++t) {
        b1v[t] = *(const f32x4*)&bias_lds[0][8 * lg + 4 * t];   // sigma-striped n
        b2v[t] = *(const f32x4*)&bias_lds[1][t * 16 + 4 * lg];
        w3v[t] = *(const f32x4*)&w3_lds[t * 16 + 4 * lg];
    }
    const float b3s = b3[0];
    const int pbase = blockIdx.x * PPB;
    float* const outp = out + pbase;
    const f32x4* const dbase = (const f32x4*)data + 2 * lg;   // lane's feat slice

#pragma unroll 1
    for (int pxg = 0; pxg < 4; ++pxg) {
        const int px = pxg * 16 + lr;
        const int p  = pbase + px;
        // ---- direct gather: this lane's 8 feats of its pixel ----
        const int ix0 = x0a[p], iy0 = y0a[p], ix1 = x1a[p], iy1 = y1a[p];
        const float2 w2 = *(const float2*)(lerp_w + 2 * p);
        const float wx = w2.x, wy = w2.y;
        const float w00 = (1.0f - wx) * (1.0f - wy);
        const float w01 = wx * (1.0f - wy);
        const float w10 = (1.0f - wx) * wy;
        const float w11 = wx * wy;
        const f32x4* c00 = dbase + (iy0 * 512 + ix0) * 8;
        const f32x4* c01 = dbase + (iy0 * 512 + ix1) * 8;
        const f32x4* c10 = dbase + (iy1 * 512 + ix0) * 8;
        const f32x4* c11 = dbase + (iy1 * 512 + ix1) * 8;
        const f32x4 ff0 = c00[0] * w00 + c01[0] * w01 + c10[0] * w10 + c11[0] * w11;
        const f32x4 ff1 = c00[1] * w00 + c01[1] * w01 + c10[1] * w10 + c11[1] * w11;

#pragma unroll
        for (int bb = 0; bb < 2; ++bb) {
            // e^T B-frag: e = f .* zf (f32), truncate-pack hi only (2-term L1)
            const f32x4 ea = ff0 * zva[bb];
            const f32x4 eb = ff1 * zvb[bb];
            FragU Eh;
            Eh.u[0] = pack_top16(ea[0], ea[1]);
            Eh.u[1] = pack_top16(ea[2], ea[3]);
            Eh.u[2] = pack_top16(eb[0], eb[1]);
            Eh.u[3] = pack_top16(eb[2], eb[3]);
            // L1 (bias as C-in): acc[t] reg r holds n = 8lg + r + 4t
            f32x4 hv[2];
#pragma unroll
            for (int t = 0; t < 2; ++t) {
                f32x4 a = __builtin_amdgcn_mfma_f32_16x16x32_bf16(W1f[t][1].s, Eh.s, b1v[t], 0, 0, 0);
                a = __builtin_amdgcn_mfma_f32_16x16x32_bf16(W1f[t][0].s, Eh.s, a, 0, 0, 0);
#pragma unroll
                for (int r = 0; r < 4; ++r) a[r] = fmaxf(a[r], 0.0f);
                hv[t] = a;
            }
            // lane holds h[8lg .. 8lg+7] = L2 B-frag k-run. Split hi/lo.
            FragU Hh, Hl;
            Hh.u[0] = pack_top16(hv[0][0], hv[0][1]);
            Hh.u[1] = pack_top16(hv[0][2], hv[0][3]);
            Hh.u[2] = pack_top16(hv[1][0], hv[1][1]);
            Hh.u[3] = pack_top16(hv[1][2], hv[1][3]);
            f32x4 hl0 = hv[0], hl1 = hv[1];
#pragma unroll
            for (int r = 0; r < 4; ++r) {
                hl0[r] -= trunc_bf16(hv[0][r]);
                hl1[r] -= trunc_bf16(hv[1][r]);
            }
            Hl.u[0] = pack_top16(hl0[0], hl0[1]);
            Hl.u[1] = pack_top16(hl0[2], hl0[3]);
            Hl.u[2] = pack_top16(hl1[0], hl1[1]);
            Hl.u[3] = pack_top16(hl1[2], hl1[3]);
            // L2: 3-term, bias as C-in, contiguous n-tiles
            float o = 0.0f;
#pragma unroll
            for (int t = 0; t < 2; ++t) {
                f32x4 a = __builtin_amdgcn_mfma_f32_16x16x32_bf16(W2f[t][0].s, Hl.s, b2v[t], 0, 0, 0);
                a = __builtin_amdgcn_mfma_f32_16x16x32_bf16(W2f[t][1].s, Hh.s, a, 0, 0, 0);
                a = __builtin_amdgcn_mfma_f32_16x16x32_bf16(W2f[t][0].s, Hh.s, a, 0, 0, 0);
#pragma unroll
                for (int r = 0; r < 4; ++r)
                    o = fmaf(fmaxf(a[r], 0.0f), w3v[t][r], o);
            }
            // L3 reduce across lg groups (lanes lr, lr+16, lr+32, lr+48)
            o += __shfl_xor(o, 16);
            o += __shfl_xor(o, 32);
            o += b3s;
            if (l < 16)
                __builtin_nontemporal_store(o, outp + (2 * w + bb) * NPIX + px);
        }
    }
}

extern "C" void kernel_launch(void* const* d_in, const int* in_sizes, int n_in,
                              void* d_out, int out_size, void* d_ws, size_t ws_size,
                              hipStream_t stream) {
    const float* zp      = (const float*)d_in[0];
    const float* data    = (const float*)d_in[1];
    const float* z_data  = (const float*)d_in[2];
    const float* lerp_w  = (const float*)d_in[3];
    const int*   x0      = (const int*)d_in[4];
    const int*   y0      = (const int*)d_in[5];
    const int*   x1      = (const int*)d_in[6];
    const int*   y1      = (const int*)d_in[7];
    const float* W1      = (const float*)d_in[8];
    const float* b1      = (const float*)d_in[9];
    const float* W2      = (const float*)d_in[10];
    const float* b2      = (const float*)d_in[11];
    const float* W3      = (const float*)d_in[12];
    const float* b3      = (const float*)d_in[13];
    float* out = (float*)d_out;

    dim3 grid(NPIX / PPB);   // 4096 blocks
    dim3 block(256);
    hipLaunchKernelGGL(field_mlp_mfma6, grid, block, 0, stream,
                       zp, data, z_data, lerp_w, x0, y0, x1, y1,
                       W1, b1, W2, b2, W3, b3, out);
}